// Round 1
// 10673.847 us; speedup vs baseline: 1.8347x; 1.8347x over previous
//
#include <hip/hip_runtime.h>

// LSTM: S=512, B=64, IN=H=1024, 2 layers sharing weight_ih/weight_hh/bias.
// Persistent kernel, layers software-pipelined (layer0 step s, layer1 step s-1).
// Cross-block h exchange uses AGENT-scope per-access coherent atomics (sc0sc1).
// Grid barrier: distributed per-block flag array (monotone step counter),
//   - NO atomic RMW (was: 256 serialized fetch-adds on one LLC line per step)
//   - NO release fence (was: buffer_wbl2 L2-writeback per block per step)
//   Each of 256 threads polls one distinct block's flag -> parallel detection.
// Cross-wave K-reduction: single __syncthreads, 4 partial areas summed in the
// cell update (was: 4-sync dump/add ladder).

typedef __attribute__((ext_vector_type(8))) short short8;
typedef __attribute__((ext_vector_type(16))) float f32x16;

#define NBLK 256

__device__ __forceinline__ short f2bf(float f) {
  unsigned u = __float_as_uint(f);
  u += 0x7FFFu + ((u >> 16) & 1u);   // RTNE
  return (short)(u >> 16);
}
__device__ __forceinline__ float fsig(float x) { return 1.0f / (1.0f + __expf(-x)); }
__device__ __forceinline__ float ftanh(float x) {
  float ax = fabsf(x);
  float e = __expf(-2.0f * ax);
  float t = (1.0f - e) / (1.0f + e);
  return x < 0.0f ? -t : t;
}

// ---------------- prep kernels ----------------

__global__ void cast_x(const float* __restrict__ x, short* __restrict__ xbf, int n8) {
  int i = blockIdx.x * blockDim.x + threadIdx.x;
  if (i >= n8) return;
  const float4* p = (const float4*)x + (size_t)i * 2;
  float4 a = p[0], b = p[1];
  short8 o;
  o[0] = f2bf(a.x); o[1] = f2bf(a.y); o[2] = f2bf(a.z); o[3] = f2bf(a.w);
  o[4] = f2bf(b.x); o[5] = f2bf(b.y); o[6] = f2bf(b.z); o[7] = f2bf(b.w);
  ((short8*)xbf)[i] = o;
}

// Pack W = [W_ih | W_hh] (4096 x 2048) into MFMA B-fragment order, bf16.
__global__ void pack_w(const float* __restrict__ wih, const float* __restrict__ whh,
                       short* __restrict__ wp) {
  int p = blockIdx.x * blockDim.x + threadIdx.x;   // < 128*128*64
  if (p >= 128 * 128 * 64) return;
  int hb = p >> 13;
  int rem = p & 8191;
  int k4 = rem >> 6;
  int lane = rem & 63;
  int colp = lane & 31;
  int sub = lane >> 5;
  int type = colp >> 3;
  int u = colp & 7;
  int jrow = type * 1024 + hb * 8 + u;
  int k0 = k4 * 16 + sub * 8;
  const float* src = (k0 < 1024) ? (wih + (size_t)jrow * 1024 + k0)
                                 : (whh + (size_t)jrow * 1024 + (k0 - 1024));
  short8 o;
#pragma unroll
  for (int j = 0; j < 8; ++j) o[j] = f2bf(src[j]);
  ((short8*)wp)[p] = o;
}

__global__ void pack_bias(const float* __restrict__ bih, const float* __restrict__ bhh,
                          float* __restrict__ bpk) {
  int i = blockIdx.x * blockDim.x + threadIdx.x;
  if (i >= 4096) return;
  int hb = i >> 5, colp = i & 31;
  int j = (colp >> 3) * 1024 + hb * 8 + (colp & 7);
  bpk[i] = bih[j] + bhh[j];
}

// ---------------- coherent / plain A-fragment load ----------------
template<bool COH>
__device__ __forceinline__ short8 ldA(const short* p) {
  if constexpr (COH) {
    union { unsigned long long u[2]; short8 v; } t;
    const unsigned long long* q = (const unsigned long long*)p;
    t.u[0] = __hip_atomic_load(q,     __ATOMIC_RELAXED, __HIP_MEMORY_SCOPE_AGENT);
    t.u[1] = __hip_atomic_load(q + 1, __ATOMIC_RELAXED, __HIP_MEMORY_SCOPE_AGENT);
    return t.v;
  } else {
    return *(const short8*)p;
  }
}

// Double-buffered, depth-1-group software pipeline: ~64 VMEM ops in flight
// (vmcnt cap) so LLC latency overlaps MFMA. All indices static after unroll.
template<bool COH>
__device__ __forceinline__ void gemm32(const short* ar0, const short* ar1,
                                       const short8* wgl, f32x16& acc0, f32x16& acc1) {
  short8 a0[2][8], a1[2][8], bw[2][8];
#pragma unroll
  for (int j = 0; j < 8; ++j) {
    a0[0][j] = ldA<COH>(ar0 + j * 16);
    a1[0][j] = ldA<COH>(ar1 + j * 16);
    bw[0][j] = wgl[j * 64];
  }
#pragma unroll
  for (int g = 0; g < 4; ++g) {
    const int cur = g & 1, nxt = cur ^ 1;
    if (g < 3) {
#pragma unroll
      for (int j = 0; j < 8; ++j) {
        const int ks = (g + 1) * 8 + j;
        a0[nxt][j] = ldA<COH>(ar0 + ks * 16);
        a1[nxt][j] = ldA<COH>(ar1 + ks * 16);
        bw[nxt][j] = wgl[ks * 64];
      }
    }
#pragma unroll
    for (int j = 0; j < 8; ++j) {
      acc0 = __builtin_amdgcn_mfma_f32_32x32x16_bf16(a0[cur][j], bw[cur][j], acc0, 0, 0, 0);
      acc1 = __builtin_amdgcn_mfma_f32_32x32x16_bf16(a1[cur][j], bw[cur][j], acc1, 0, 0, 0);
    }
  }
}

// ---------------- persistent LSTM kernel ----------------
// 256 blocks x 256 threads (1 block/CU). Block = (layer = bid>>7, hb = bid&127).
// 64 rows x 32 cols (8 hidden units x 4 gates), K=2048 split across 4 waves.
__global__ __launch_bounds__(256, 1)
void lstm_loop(const short* __restrict__ xbf, const short* __restrict__ wp,
               const float* __restrict__ bpk, short* __restrict__ h0buf,
               short* __restrict__ h1buf, float* __restrict__ out,
               unsigned* __restrict__ flags)
{
  const int bid = blockIdx.x;
  const int layer = bid >> 7;
  const int hb = bid & 127;
  const int tid = threadIdx.x;
  const int lane = tid & 63;
  const int wv = tid >> 6;        // 0..3 = K-quarter
  const int col = lane & 31;
  const int sub = lane >> 5;

  __shared__ float red[4][64 * 33];   // per-wave partial gate sums

  const short8* wgl = (const short8*)(wp + (size_t)hb * 65536) + (size_t)(wv * 32) * 64 + lane;

  // state-update assignment: thread -> (row = tid>>2, unit pair = tid&3)
  const int r = tid >> 2;
  const int p2 = tid & 3;
  const int u0 = p2 * 2, u1 = u0 + 1;
  const float bi0 = bpk[hb * 32 + u0],      bi1 = bpk[hb * 32 + u1];
  const float bf0 = bpk[hb * 32 + 8 + u0],  bf1 = bpk[hb * 32 + 8 + u1];
  const float bg0 = bpk[hb * 32 + 16 + u0], bg1 = bpk[hb * 32 + 16 + u1];
  const float bo0 = bpk[hb * 32 + 24 + u0], bo1 = bpk[hb * 32 + 24 + u1];
  const int hg = hb * 8 + u0;     // global unit index (even)
  float c0v = 0.0f, c1v = 0.0f;   // cell state in registers

  const int kbase = (wv & 1) * 512;
  const bool coh = !(layer == 0 && wv < 2);   // x-half is plain cached; h-halves coherent

  const unsigned* myflag = flags + (size_t)tid * 16;   // 64B-strided, 1 flag/thread

  for (int s = 0; s < 513; ++s) {
    const bool active = (layer == 0) ? (s < 512) : (s >= 1);
    const int t = (layer == 0) ? s : (s - 1);
    if (active) {
      const short* A0 = (layer == 0) ? (xbf + (size_t)t * 65536)
                                     : (h0buf + (size_t)(t & 1) * 65536);
      const short* A1 = (layer == 0) ? (h0buf + (size_t)((t + 1) & 1) * 65536)
                                     : (h1buf + (size_t)((t + 1) & 1) * 65536);
      const short* Ah = (wv < 2) ? A0 : A1;
      const short* ar0 = Ah + (size_t)col * 1024 + kbase + sub * 8;
      const short* ar1 = ar0 + 32 * 1024;

      f32x16 acc0, acc1;
#pragma unroll
      for (int rr = 0; rr < 16; ++rr) { acc0[rr] = 0.0f; acc1[rr] = 0.0f; }

      if (coh) gemm32<true>(ar0, ar1, wgl, acc0, acc1);
      else     gemm32<false>(ar0, ar1, wgl, acc0, acc1);

      // single-sync cross-wave K reduction:
      // each wave dumps its partial (C layout: col=lane&31, row=(r&3)+8*(r>>2)+4*sub)
#pragma unroll
      for (int rr = 0; rr < 16; ++rr) {
        int q = (rr & 3) + 8 * (rr >> 2) + 4 * sub;
        red[wv][q * 33 + col] = acc0[rr];
        red[wv][(q + 32) * 33 + col] = acc1[rr];
      }
      __syncthreads();

      // LSTM cell update: row r, units u0,u1; sum 4 partials inline
      const int b0 = r * 33;
      auto rsum = [&](int off) {
        return red[0][b0 + off] + red[1][b0 + off] + red[2][b0 + off] + red[3][b0 + off];
      };
      float pi0 = rsum(u0) + bi0;
      float pf0 = rsum(8 + u0) + bf0;
      float pg0 = rsum(16 + u0) + bg0;
      float po0 = rsum(24 + u0) + bo0;
      float ig0 = fsig(pi0), fg0 = fsig(pf0), gg0 = ftanh(pg0), og0 = fsig(po0);
      c0v = fg0 * c0v + ig0 * gg0;
      float h0v = og0 * ftanh(c0v);

      float pi1 = rsum(u1) + bi1;
      float pf1 = rsum(8 + u1) + bf1;
      float pg1 = rsum(16 + u1) + bg1;
      float po1 = rsum(24 + u1) + bo1;
      float ig1 = fsig(pi1), fg1 = fsig(pf1), gg1 = ftanh(pg1), og1 = fsig(po1);
      c1v = fg1 * c1v + ig1 * gg1;
      float h1v = og1 * ftanh(c1v);

      // coherent packed h store (2 bf16 per uint)
      unsigned hp = (unsigned)(unsigned short)f2bf(h0v)
                  | ((unsigned)(unsigned short)f2bf(h1v) << 16);
      unsigned* hw = (unsigned*)(((layer == 0) ? h0buf : h1buf) + (size_t)(t & 1) * 65536)
                   + ((r * 1024 + hg) >> 1);
      __hip_atomic_store(hw, hp, __ATOMIC_RELAXED, __HIP_MEMORY_SCOPE_AGENT);

      if (layer == 1) {
        float2 o2 = make_float2(h0v, h1v);
        *(float2*)(out + (size_t)t * 65536 + r * 1024 + hg) = o2;
      }
      if (t == 511) {
        const size_t HN = 33554432;         // outputs elements
        const size_t CN = HN + 131072;      // + h_n elements
        *(float2*)(out + HN + (size_t)layer * 65536 + r * 1024 + hg) = make_float2(h0v, h1v);
        *(float2*)(out + CN + (size_t)layer * 65536 + r * 1024 + hg) = make_float2(c0v, c1v);
      }
    }

    // ---- grid barrier: distributed flag array (no RMW, no release fence) ----
    __syncthreads();   // compiler drains vmcnt(0): h stores at LLC before signal
    if (tid == 0) {
      asm volatile("s_waitcnt vmcnt(0)" ::: "memory");
      __hip_atomic_store(flags + (size_t)bid * 16, (unsigned)(s + 1),
                         __ATOMIC_RELAXED, __HIP_MEMORY_SCOPE_AGENT);
    }
    {
      const unsigned tgt = (unsigned)(s + 1);
      while (__hip_atomic_load(myflag, __ATOMIC_RELAXED, __HIP_MEMORY_SCOPE_AGENT) < tgt)
        __builtin_amdgcn_s_sleep(1);
    }
    __syncthreads();   // all 256 flags verified collectively
    // no acquire fence: subsequent cross-block reads are sc0sc1 coherent loads
  }
}

// ---------------- launch ----------------
extern "C" void kernel_launch(void* const* d_in, const int* in_sizes, int n_in,
                              void* d_out, int out_size, void* d_ws, size_t ws_size,
                              hipStream_t stream) {
  const float* x = (const float*)d_in[0];
  const float* wih = (const float*)d_in[1];
  const float* whh = (const float*)d_in[2];
  const float* bih = (const float*)d_in[3];
  const float* bhh = (const float*)d_in[4];
  float* outf = (float*)d_out;
  char* ws = (char*)d_ws;

  short* xbf = (short*)(ws);                       // 67,108,864 B
  short* wp = (short*)(ws + 67108864);             // 33,554,432 B
  float* bpk = (float*)(ws + 100663296);           // 16,384 B
  short* h0buf = (short*)(ws + 100679680);         // 262,144 B (2 parities)
  short* h1buf = (short*)(ws + 100941824);         // 262,144 B
  unsigned* flags = (unsigned*)(ws + 101203968);   // 256 x 64 B flag slots

  hipMemsetAsync(h0buf, 0, 524288 + 16384, stream);

  cast_x<<<16384, 256, 0, stream>>>(x, xbf, 4194304);
  pack_w<<<4096, 256, 0, stream>>>(wih, whh, wp);
  pack_bias<<<16, 256, 0, stream>>>(bih, bhh, bpk);

  lstm_loop<<<dim3(NBLK), dim3(256), 0, stream>>>(xbf, wp, bpk, h0buf, h1buf, outf, flags);
}

// Round 3
// 5895.316 us; speedup vs baseline: 3.3219x; 1.8106x over previous
//
#include <hip/hip_runtime.h>

// LSTM: S=512, B=64, IN=H=1024, 2 layers sharing weight_ih/weight_hh/bias.
// Persistent kernel, layers software-pipelined (layer0 step s, layer1 step s-1).
// Cross-block h exchange: AGENT-scope coherent accesses (sc0 sc1 -> LLC).
// Grid barrier: distributed per-block flag array (no RMW, no release fence).
// Round 3: counted-vmcnt asm load pipeline, DE-RISKED vs round 2:
//   - groups of 8 loads (4 K-slices x 2 row-halves), depth-2 -> 16 outstanding,
//     64 staging VGPRs (was 128; total ~270 VGPR, no spill risk -> vmcnt
//     counting invariant safe)
//   - "=&v" early-clobber on asm load outputs
//   - weights preloaded into 128 VGPRs (live across all 513 steps)
//   - sched_barrier(0) after each counted wait (rule: MFMA hoists past asm
//     waitcnt otherwise) and after each MFMA group (pins issue order)

typedef __attribute__((ext_vector_type(8))) short short8;
typedef __attribute__((ext_vector_type(16))) float f32x16;

#define NBLK 256

__device__ __forceinline__ short f2bf(float f) {
  unsigned u = __float_as_uint(f);
  u += 0x7FFFu + ((u >> 16) & 1u);   // RTNE
  return (short)(u >> 16);
}
__device__ __forceinline__ float fsig(float x) { return 1.0f / (1.0f + __expf(-x)); }
__device__ __forceinline__ float ftanh(float x) {
  float ax = fabsf(x);
  float e = __expf(-2.0f * ax);
  float t = (1.0f - e) / (1.0f + e);
  return x < 0.0f ? -t : t;
}

// ---------------- prep kernels ----------------

__global__ void cast_x(const float* __restrict__ x, short* __restrict__ xbf, int n8) {
  int i = blockIdx.x * blockDim.x + threadIdx.x;
  if (i >= n8) return;
  const float4* p = (const float4*)x + (size_t)i * 2;
  float4 a = p[0], b = p[1];
  short8 o;
  o[0] = f2bf(a.x); o[1] = f2bf(a.y); o[2] = f2bf(a.z); o[3] = f2bf(a.w);
  o[4] = f2bf(b.x); o[5] = f2bf(b.y); o[6] = f2bf(b.z); o[7] = f2bf(b.w);
  ((short8*)xbf)[i] = o;
}

// Pack W = [W_ih | W_hh] (4096 x 2048) into MFMA B-fragment order, bf16.
__global__ void pack_w(const float* __restrict__ wih, const float* __restrict__ whh,
                       short* __restrict__ wp) {
  int p = blockIdx.x * blockDim.x + threadIdx.x;   // < 128*128*64
  if (p >= 128 * 128 * 64) return;
  int hb = p >> 13;
  int rem = p & 8191;
  int k4 = rem >> 6;
  int lane = rem & 63;
  int colp = lane & 31;
  int sub = lane >> 5;
  int type = colp >> 3;
  int u = colp & 7;
  int jrow = type * 1024 + hb * 8 + u;
  int k0 = k4 * 16 + sub * 8;
  const float* src = (k0 < 1024) ? (wih + (size_t)jrow * 1024 + k0)
                                 : (whh + (size_t)jrow * 1024 + (k0 - 1024));
  short8 o;
#pragma unroll
  for (int j = 0; j < 8; ++j) o[j] = f2bf(src[j]);
  ((short8*)wp)[p] = o;
}

__global__ void pack_bias(const float* __restrict__ bih, const float* __restrict__ bhh,
                          float* __restrict__ bpk) {
  int i = blockIdx.x * blockDim.x + threadIdx.x;
  if (i >= 4096) return;
  int hb = i >> 5, colp = i & 31;
  int j = (colp >> 3) * 1024 + hb * 8 + (colp & 7);
  bpk[i] = bih[j] + bhh[j];
}

// ---------------- asm load pipeline ----------------

template<bool COH, int OFF>
__device__ __forceinline__ short8 ldAasm(const short* p) {
  short8 d;
  if constexpr (COH)
    asm volatile("global_load_dwordx4 %0, %1, off offset:%2 sc0 sc1"
                 : "=&v"(d) : "v"(p), "n"(OFF));
  else
    asm volatile("global_load_dwordx4 %0, %1, off offset:%2"
                 : "=&v"(d) : "v"(p), "n"(OFF));
  return d;
}

#define WAITV(n) do { asm volatile("s_waitcnt vmcnt(" #n ")" ::: "memory"); \
                      __builtin_amdgcn_sched_barrier(0); } while (0)
#define SB() __builtin_amdgcn_sched_barrier(0)

// Issue one group: 4 K-slices x 2 row-halves = 8 loads.
template<bool COH, int G>
__device__ __forceinline__ void issue_group(const short* ar0, const short* ar1,
                                            short8 (&b0)[4], short8 (&b1)[4]) {
#define ISSUE2(j) \
  b0[j] = ldAasm<COH, (G * 4 + (j)) * 32>(ar0); \
  b1[j] = ldAasm<COH, (G * 4 + (j)) * 32>(ar1);
  ISSUE2(0) ISSUE2(1) ISSUE2(2) ISSUE2(3)
#undef ISSUE2
}

template<int G>
__device__ __forceinline__ void mfma_group(const short8 (&b0)[4], const short8 (&b1)[4],
                                           const short8 (&w)[32], f32x16& acc0, f32x16& acc1) {
#pragma unroll
  for (int j = 0; j < 4; ++j) {
    acc0 = __builtin_amdgcn_mfma_f32_32x32x16_bf16(b0[j], w[G * 4 + j], acc0, 0, 0, 0);
    acc1 = __builtin_amdgcn_mfma_f32_32x32x16_bf16(b1[j], w[G * 4 + j], acc1, 0, 0, 0);
  }
}

// 32 K-slices, weights preloaded in registers, 8 groups, depth-2 pipeline.
// Max 16 VMEM outstanding. No other VMEM may be issued between the asm loads
// and the waits (counting invariant; ~270 total VGPRs -> no spill traffic).
template<bool COH>
__device__ __forceinline__ void gemm32p(const short* ar0, const short* ar1,
                                        const short8 (&w)[32], f32x16& acc0, f32x16& acc1) {
  short8 p0[4], p1[4], q0[4], q1[4];
  issue_group<COH, 0>(ar0, ar1, p0, p1);           //  8 in flight
  issue_group<COH, 1>(ar0, ar1, q0, q1);           // 16 in flight
  WAITV(8);  mfma_group<0>(p0, p1, w, acc0, acc1); SB();
  issue_group<COH, 2>(ar0, ar1, p0, p1);           // 16 in flight
  WAITV(8);  mfma_group<1>(q0, q1, w, acc0, acc1); SB();
  issue_group<COH, 3>(ar0, ar1, q0, q1);
  WAITV(8);  mfma_group<2>(p0, p1, w, acc0, acc1); SB();
  issue_group<COH, 4>(ar0, ar1, p0, p1);
  WAITV(8);  mfma_group<3>(q0, q1, w, acc0, acc1); SB();
  issue_group<COH, 5>(ar0, ar1, q0, q1);
  WAITV(8);  mfma_group<4>(p0, p1, w, acc0, acc1); SB();
  issue_group<COH, 6>(ar0, ar1, p0, p1);
  WAITV(8);  mfma_group<5>(q0, q1, w, acc0, acc1); SB();
  issue_group<COH, 7>(ar0, ar1, q0, q1);
  WAITV(8);  mfma_group<6>(p0, p1, w, acc0, acc1); SB();
  WAITV(0);  mfma_group<7>(q0, q1, w, acc0, acc1);
}

// ---------------- persistent LSTM kernel ----------------
// 256 blocks x 256 threads (1 block/CU). Block = (layer = bid>>7, hb = bid&127).
// 64 rows x 32 cols (8 hidden units x 4 gates), K=2048 split across 4 waves.
__global__ __launch_bounds__(256, 1)
void lstm_loop(const short* __restrict__ xbf, const short* __restrict__ wp,
               const float* __restrict__ bpk, short* __restrict__ h0buf,
               short* __restrict__ h1buf, float* __restrict__ out,
               unsigned* __restrict__ flags)
{
  const int bid = blockIdx.x;
  const int layer = bid >> 7;
  const int hb = bid & 127;
  const int tid = threadIdx.x;
  const int lane = tid & 63;
  const int wv = tid >> 6;        // 0..3 = K-quarter
  const int col = lane & 31;
  const int sub = lane >> 5;

  __shared__ float red[4][64 * 37];   // per-wave partial gate sums (pad 37)

  const short8* wgl = (const short8*)(wp + (size_t)hb * 65536) + (size_t)(wv * 32) * 64 + lane;

  // Preload this wave's weight slice into registers: 32 x short8 = 128 VGPRs,
  // live across all 513 steps. Removes 1/3 of per-step loads + all W traffic.
  short8 wreg[32];
#pragma unroll
  for (int i = 0; i < 32; ++i) wreg[i] = wgl[i * 64];

  // state-update assignment: thread -> (row = tid>>2, unit pair = tid&3)
  const int r = tid >> 2;
  const int p2 = tid & 3;
  const int u0 = p2 * 2, u1 = u0 + 1;
  const float bi0 = bpk[hb * 32 + u0],      bi1 = bpk[hb * 32 + u1];
  const float bf0 = bpk[hb * 32 + 8 + u0],  bf1 = bpk[hb * 32 + 8 + u1];
  const float bg0 = bpk[hb * 32 + 16 + u0], bg1 = bpk[hb * 32 + 16 + u1];
  const float bo0 = bpk[hb * 32 + 24 + u0], bo1 = bpk[hb * 32 + 24 + u1];
  const int hg = hb * 8 + u0;     // global unit index (even)
  float c0v = 0.0f, c1v = 0.0f;   // cell state in registers

  const int kbase = (wv & 1) * 512;
  const bool coh = !(layer == 0 && wv < 2);   // x-half is plain cached; h-halves coherent

  const unsigned* myflag = flags + (size_t)tid * 16;   // 64B-strided, 1 flag/thread

  for (int s = 0; s < 513; ++s) {
    const bool active = (layer == 0) ? (s < 512) : (s >= 1);
    const int t = (layer == 0) ? s : (s - 1);
    if (active) {
      const short* A0 = (layer == 0) ? (xbf + (size_t)t * 65536)
                                     : (h0buf + (size_t)(t & 1) * 65536);
      const short* A1 = (layer == 0) ? (h0buf + (size_t)((t + 1) & 1) * 65536)
                                     : (h1buf + (size_t)((t + 1) & 1) * 65536);
      const short* Ah = (wv < 2) ? A0 : A1;
      const short* ar0 = Ah + (size_t)col * 1024 + kbase + sub * 8;
      const short* ar1 = ar0 + 32 * 1024;

      f32x16 acc0, acc1;
#pragma unroll
      for (int rr = 0; rr < 16; ++rr) { acc0[rr] = 0.0f; acc1[rr] = 0.0f; }

      if (coh) gemm32p<true>(ar0, ar1, wreg, acc0, acc1);
      else     gemm32p<false>(ar0, ar1, wreg, acc0, acc1);

      // single-sync cross-wave K reduction:
      // each wave dumps its partial (C layout: col=lane&31, row=(r&3)+8*(r>>2)+4*sub)
#pragma unroll
      for (int rr = 0; rr < 16; ++rr) {
        int q = (rr & 3) + 8 * (rr >> 2) + 4 * sub;
        red[wv][q * 37 + col] = acc0[rr];
        red[wv][(q + 32) * 37 + col] = acc1[rr];
      }
      __syncthreads();

      // LSTM cell update: row r, units u0,u1; sum 4 partials inline
      const int b0 = r * 37;
      auto rsum = [&](int off) {
        return red[0][b0 + off] + red[1][b0 + off] + red[2][b0 + off] + red[3][b0 + off];
      };
      float pi0 = rsum(u0) + bi0;
      float pf0 = rsum(8 + u0) + bf0;
      float pg0 = rsum(16 + u0) + bg0;
      float po0 = rsum(24 + u0) + bo0;
      float ig0 = fsig(pi0), fg0 = fsig(pf0), gg0 = ftanh(pg0), og0 = fsig(po0);
      c0v = fg0 * c0v + ig0 * gg0;
      float h0v = og0 * ftanh(c0v);

      float pi1 = rsum(u1) + bi1;
      float pf1 = rsum(8 + u1) + bf1;
      float pg1 = rsum(16 + u1) + bg1;
      float po1 = rsum(24 + u1) + bo1;
      float ig1 = fsig(pi1), fg1 = fsig(pf1), gg1 = ftanh(pg1), og1 = fsig(po1);
      c1v = fg1 * c1v + ig1 * gg1;
      float h1v = og1 * ftanh(c1v);

      // coherent packed h store (2 bf16 per uint)
      unsigned hp = (unsigned)(unsigned short)f2bf(h0v)
                  | ((unsigned)(unsigned short)f2bf(h1v) << 16);
      unsigned* hw = (unsigned*)(((layer == 0) ? h0buf : h1buf) + (size_t)(t & 1) * 65536)
                   + ((r * 1024 + hg) >> 1);
      __hip_atomic_store(hw, hp, __ATOMIC_RELAXED, __HIP_MEMORY_SCOPE_AGENT);

      if (layer == 1) {
        float2 o2 = make_float2(h0v, h1v);
        *(float2*)(out + (size_t)t * 65536 + r * 1024 + hg) = o2;
      }
      if (t == 511) {
        const size_t HN = 33554432;         // outputs elements
        const size_t CN = HN + 131072;      // + h_n elements
        *(float2*)(out + HN + (size_t)layer * 65536 + r * 1024 + hg) = make_float2(h0v, h1v);
        *(float2*)(out + CN + (size_t)layer * 65536 + r * 1024 + hg) = make_float2(c0v, c1v);
      }
    }

    // ---- grid barrier: distributed flag array (no RMW, no release fence) ----
    __syncthreads();   // drains vmcnt(0): h stores at LLC before signal
    if (tid == 0) {
      asm volatile("s_waitcnt vmcnt(0)" ::: "memory");
      __hip_atomic_store(flags + (size_t)bid * 16, (unsigned)(s + 1),
                         __ATOMIC_RELAXED, __HIP_MEMORY_SCOPE_AGENT);
    }
    {
      const unsigned tgt = (unsigned)(s + 1);
      while (__hip_atomic_load(myflag, __ATOMIC_RELAXED, __HIP_MEMORY_SCOPE_AGENT) < tgt)
        __builtin_amdgcn_s_sleep(1);
    }
    __syncthreads();   // all 256 flags verified collectively
    // no acquire fence: subsequent cross-block reads are sc0sc1 coherent loads
  }
}

// ---------------- launch ----------------
extern "C" void kernel_launch(void* const* d_in, const int* in_sizes, int n_in,
                              void* d_out, int out_size, void* d_ws, size_t ws_size,
                              hipStream_t stream) {
  const float* x = (const float*)d_in[0];
  const float* wih = (const float*)d_in[1];
  const float* whh = (const float*)d_in[2];
  const float* bih = (const float*)d_in[3];
  const float* bhh = (const float*)d_in[4];
  float* outf = (float*)d_out;
  char* ws = (char*)d_ws;

  short* xbf = (short*)(ws);                       // 67,108,864 B
  short* wp = (short*)(ws + 67108864);             // 33,554,432 B
  float* bpk = (float*)(ws + 100663296);           // 16,384 B
  short* h0buf = (short*)(ws + 100679680);         // 262,144 B (2 parities)
  short* h1buf = (short*)(ws + 100941824);         // 262,144 B
  unsigned* flags = (unsigned*)(ws + 101203968);   // 256 x 64 B flag slots

  hipMemsetAsync(h0buf, 0, 524288 + 16384, stream);

  cast_x<<<16384, 256, 0, stream>>>(x, xbf, 4194304);
  pack_w<<<4096, 256, 0, stream>>>(wih, whh, wp);
  pack_bias<<<16, 256, 0, stream>>>(bih, bhh, bpk);

  lstm_loop<<<dim3(NBLK), dim3(256), 0, stream>>>(xbf, wp, bpk, h0buf, h1buf, outf, flags);
}